// Round 4
// baseline (12553.494 us; speedup 1.0000x reference)
//
#include <hip/hip_runtime.h>

#define NN 10368
#define EE 207360
#define TT 16

// ---- workspace layout (float offsets) ---- total ~6.1M floats = 24.4 MB
#define O_W0AT    0
#define O_W0BT    9216
#define O_WHHT    18432
#define O_WIHXT   55296
#define O_WCOMBT  92160
#define O_GB      129024
#define O_LOSS    129408
#define O_H       129424
#define O_C       (O_H  + NN*96)
#define O_A       (O_C  + NN*96)
#define O_BV      (O_A  + NN*96)
#define O_S2      (O_BV + NN*96)
#define O_X       (O_S2 + NN*96)

__device__ __forceinline__ float sigm(float x){ return 1.f/(1.f + expf(-x)); }

// ---------- prep: weight transposes + loss zero ----------
__global__ void k_convert(float* ws, const float* msgW0, const float* Whh, const float* Wih)
{
  int i = blockIdx.x*256 + threadIdx.x;
  if (i < 9216){ int k=i/96, j=i%96; ws[O_W0AT+i] = msgW0[j*192+k];    return; } i -= 9216;
  if (i < 9216){ int k=i/96, j=i%96; ws[O_W0BT+i] = msgW0[j*192+96+k]; return; } i -= 9216;
  if (i < 36864){ int k=i/384, j=i%384; ws[O_WHHT+i]  = Whh[j*96+k];   return; } i -= 36864;
  if (i < 36864){ int k=i/384, j=i%384; ws[O_WIHXT+i] = Wih[j*192+k];  return; } i -= 36864;
  if (i == 0){ ws[O_LOSS] = 0.f; }
}

// ---------- Wcomb = W_ih[:,96:] @ msg_W[2]  (fold last msg layer into gates) ----------
__global__ void k_wcomb(float* ws, const float* Wih, const float* msgW, const float* msgb)
{
  int t = blockIdx.x*256 + threadIdx.x;
  if (t >= 36864) return;
  int j = t % 384, qq = t / 384;
  float a0=0.f,a1=0.f,a2=0.f,a3=0.f;
  for (int r=0;r<96;r+=4){
    a0 = fmaf(Wih[j*192+96+r  ], msgW[2*9216+(r  )*96+qq], a0);
    a1 = fmaf(Wih[j*192+96+r+1], msgW[2*9216+(r+1)*96+qq], a1);
    a2 = fmaf(Wih[j*192+96+r+2], msgW[2*9216+(r+2)*96+qq], a2);
    a3 = fmaf(Wih[j*192+96+r+3], msgW[2*9216+(r+3)*96+qq], a3);
  }
  ws[O_WCOMBT + qq*384 + j] = (a0+a1)+(a2+a3);
  if (qq == 0){ // gate bias fold: 20 * W_ihm @ msg_b[3]
    float g=0.f;
    for (int r=0;r<96;r++) g = fmaf(Wih[j*192+96+r], msgb[288+r], g);
    ws[O_GB + j] = 20.f * g;
  }
}

// ---------- input MLP: x = h0 = mlp4(cat(embeds)); c = 0 ----------
__global__ __launch_bounds__(64) void k_input(float* ws,
    const int* q, const int* row, const int* col,
    const float* demb, const float* remb, const float* cemb,
    const float* inW0, const float* inW, const float* inb)
{
  __shared__ float scr[96*65];
  int tid = threadIdx.x;
  int n = blockIdx.x*64 + tid;
  int qv=q[n], rv=row[n], cv=col[n];
  float in48[48];
  #pragma unroll
  for (int i=0;i<16;i++){
    in48[i]    = demb[qv*16+i];
    in48[16+i] = remb[rv*16+i];
    in48[32+i] = cemb[cv*16+i];
  }
  #pragma unroll 2
  for (int j=0;j<96;j++){
    float a0=inb[j], a1=0.f, a2=0.f, a3=0.f;
    #pragma unroll
    for (int k=0;k<48;k+=4){
      a0=fmaf(inW0[j*48+k  ],in48[k  ],a0); a1=fmaf(inW0[j*48+k+1],in48[k+1],a1);
      a2=fmaf(inW0[j*48+k+2],in48[k+2],a2); a3=fmaf(inW0[j*48+k+3],in48[k+3],a3);
    }
    scr[j*65+tid] = fmaxf((a0+a1)+(a2+a3), 0.f);
  }
  float v[96];
  #pragma unroll
  for (int k=0;k<96;k++) v[k] = scr[k*65+tid];

  for (int l=0;l<2;l++){
    const float* W = inW + l*9216;
    const float* b = inb + (l+1)*96;
    #pragma unroll 2
    for (int j=0;j<96;j++){
      float a0=b[j], a1=0.f, a2=0.f, a3=0.f;
      #pragma unroll
      for (int k=0;k<96;k+=4){
        a0=fmaf(W[j*96+k  ],v[k  ],a0); a1=fmaf(W[j*96+k+1],v[k+1],a1);
        a2=fmaf(W[j*96+k+2],v[k+2],a2); a3=fmaf(W[j*96+k+3],v[k+3],a3);
      }
      scr[j*65+tid] = fmaxf((a0+a1)+(a2+a3), 0.f);
    }
    #pragma unroll
    for (int k=0;k<96;k++) v[k] = scr[k*65+tid];
  }
  { // final layer, no relu
    const float* W = inW + 2*9216;
    const float* b = inb + 3*96;
    #pragma unroll 2
    for (int j=0;j<96;j++){
      float a0=b[j], a1=0.f, a2=0.f, a3=0.f;
      #pragma unroll
      for (int k=0;k<96;k+=4){
        a0=fmaf(W[j*96+k  ],v[k  ],a0); a1=fmaf(W[j*96+k+1],v[k+1],a1);
        a2=fmaf(W[j*96+k+2],v[k+2],a2); a3=fmaf(W[j*96+k+3],v[k+3],a3);
      }
      scr[j*65+tid] = (a0+a1)+(a2+a3);
    }
  }
  __syncthreads();
  float* h = ws + O_H; float* c = ws + O_C; float* x = ws + O_X;
  int nb = blockIdx.x*64;
  for (int idx=tid; idx<64*96; idx+=64){
    int nl = idx/96, j = idx%96;
    float vv = scr[j*65 + nl];
    h[(nb+nl)*96 + j] = vv;
    x[(nb+nl)*96 + j] = vv;
    c[(nb+nl)*96 + j] = 0.f;
  }
}

// ---------- one-time: A/B for step 0 from h0 ----------
__global__ __launch_bounds__(192) void k_ab0(float* ws, const float* msgb)
{
  int tid = threadIdx.x; int g = tid/96, j = tid%96;
  int nq = blockIdx.x*2 + g; int n0 = nq*8;
  const float* h  = ws + O_H;
  const float* WA = ws + O_W0AT;
  const float* WB = ws + O_W0BT;
  float aa[8],ab[8];
  #pragma unroll
  for (int i=0;i<8;i++){ aa[i]=0.f; ab[i]=0.f; }
  #pragma unroll 2
  for (int k=0;k<96;k++){
    float wa=WA[k*96+j],  wb=WB[k*96+j];
    #pragma unroll
    for (int i=0;i<8;i++){
      float xv = h[(n0+i)*96+k];
      aa[i]=fmaf(wa,xv,aa[i]); ab[i]=fmaf(wb,xv,ab[i]);
    }
  }
  float* A=ws+O_A; float* Bv=ws+O_BV;
  float b0v = msgb[j];
  #pragma unroll
  for (int i=0;i<8;i++){
    int n=n0+i;
    A[n*96+j]=aa[i]; Bv[n*96+j]=ab[i]+b0v;
  }
}

// ---------- per-step edge MLP + aggregation ----------
// s2[n] = sum_{v in nbr(n)} relu(W2 relu(W1 relu(A[v]+B[n])))
__global__ __launch_bounds__(128) void k_edge(float* ws, const int* dst,
                                              const float* msgW, const float* msgb)
{
  __shared__ float scr[96*129];  // per-thread column, padded stride
  int tid = threadIdx.x;
  int nb = blockIdx.x*6;                 // 6 nodes, 120 edges per block
  int e = nb*20 + tid; if (e >= EE) e = EE-1;
  int v = dst[e];
  int ln = tid/20; if (ln > 5) ln = 5;
  int n = nb + ln;

  const float* A  = ws + O_A;
  const float* Bv = ws + O_BV;
  float vin[96];
  const float4* A4 = (const float4*)(A  + v*96);
  const float4* B4 = (const float4*)(Bv + n*96);
  #pragma unroll
  for (int kk=0;kk<24;kk++){
    float4 a = A4[kk], b = B4[kk];
    vin[kk*4+0]=fmaxf(a.x+b.x,0.f); vin[kk*4+1]=fmaxf(a.y+b.y,0.f);
    vin[kk*4+2]=fmaxf(a.z+b.z,0.f); vin[kk*4+3]=fmaxf(a.w+b.w,0.f);
  }
  const float* W1 = msgW;          const float* b1 = msgb + 96;
  #pragma unroll 2
  for (int j=0;j<96;j++){
    float q0=b1[j], q1=0.f, q2=0.f, q3=0.f;
    #pragma unroll
    for (int k=0;k<96;k+=4){
      q0=fmaf(W1[j*96+k  ],vin[k  ],q0); q1=fmaf(W1[j*96+k+1],vin[k+1],q1);
      q2=fmaf(W1[j*96+k+2],vin[k+2],q2); q3=fmaf(W1[j*96+k+3],vin[k+3],q3);
    }
    scr[j*129+tid] = fmaxf((q0+q1)+(q2+q3), 0.f);
  }
  #pragma unroll
  for (int k=0;k<96;k++) vin[k] = scr[k*129+tid];

  const float* W2 = msgW + 9216;   const float* b2 = msgb + 192;
  #pragma unroll 2
  for (int j=0;j<96;j++){
    float q0=b2[j], q1=0.f, q2=0.f, q3=0.f;
    #pragma unroll
    for (int k=0;k<96;k+=4){
      q0=fmaf(W2[j*96+k  ],vin[k  ],q0); q1=fmaf(W2[j*96+k+1],vin[k+1],q1);
      q2=fmaf(W2[j*96+k+2],vin[k+2],q2); q3=fmaf(W2[j*96+k+3],vin[k+3],q3);
    }
    scr[j*129+tid] = fmaxf((q0+q1)+(q2+q3), 0.f);
  }
  __syncthreads();
  float* s2 = ws + O_S2;
  for (int idx=tid; idx<576; idx+=128){
    int node = idx/96, j = idx%96;
    const float* base = &scr[j*129 + node*20];
    float s=0.f;
    #pragma unroll
    for (int l=0;l<20;l++) s += base[l];
    s2[(nb+node)*96 + j] = s;
  }
}

// ---------- per-step: LSTM gates + state + next A/B + logits/preds/loss ----------
__global__ __launch_bounds__(192) void k_lstm(float* ws, const int* labels,
                                              const float* msgb,
                                              const float* outW, const float* outb,
                                              float* out, int t)
{
  __shared__ float lh[16*97];
  __shared__ float lgt[160];
  int tid = threadIdx.x; int g = tid/96, j = tid%96;
  int nq = blockIdx.x*2 + g; int n0 = nq*8;
  const float* WX = ws + O_WIHXT;
  const float* WC = ws + O_WCOMBT;
  const float* WH = ws + O_WHHT;
  const float* s2 = ws + O_S2;
  const float* x  = ws + O_X;
  float* h = ws + O_H; float* c = ws + O_C;

  // reference scan carry: (h, rh, rc) init (x, 0, 0) — at t=0 the recurrent
  // term uses rh=0 (NOT h=x). hscale kills the W_hh term exactly at t=0.
  const float hscale = (t == 0) ? 0.f : 1.f;

  float a0[8],a1[8],a2[8],a3[8];
  {
    float gb0=ws[O_GB+j], gb1=ws[O_GB+96+j], gb2=ws[O_GB+192+j], gb3=ws[O_GB+288+j];
    #pragma unroll
    for (int i=0;i<8;i++){ a0[i]=gb0; a1[i]=gb1; a2[i]=gb2; a3[i]=gb3; }
  }
  // phase 1: frozen-input gate term  W_ihx @ x
  #pragma unroll 2
  for (int k=0;k<96;k++){
    float w0=WX[k*384+j], w1=WX[k*384+96+j], w2=WX[k*384+192+j], w3=WX[k*384+288+j];
    #pragma unroll
    for (int i=0;i<8;i++){
      float xv = x[(n0+i)*96+k];
      a0[i]=fmaf(w0,xv,a0[i]); a1[i]=fmaf(w1,xv,a1[i]);
      a2[i]=fmaf(w2,xv,a2[i]); a3[i]=fmaf(w3,xv,a3[i]);
    }
  }
  // phase 2: message (Wcomb@s2) + recurrent (Whh@rh), rh = (t==0 ? 0 : h)
  #pragma unroll 2
  for (int k=0;k<96;k++){
    float c0=WC[k*384+j], c1=WC[k*384+96+j], c2=WC[k*384+192+j], c3=WC[k*384+288+j];
    float h0=WH[k*384+j], h1=WH[k*384+96+j], h2=WH[k*384+192+j], h3=WH[k*384+288+j];
    #pragma unroll
    for (int i=0;i<8;i++){
      float sv = s2[(n0+i)*96+k];
      float rv = h [(n0+i)*96+k] * hscale;
      a0[i]=fmaf(c0,sv,fmaf(h0,rv,a0[i]));
      a1[i]=fmaf(c1,sv,fmaf(h1,rv,a1[i]));
      a2[i]=fmaf(c2,sv,fmaf(h2,rv,a2[i]));
      a3[i]=fmaf(c3,sv,fmaf(h3,rv,a3[i]));
    }
  }
  float nh[8], ncv[8];
  #pragma unroll
  for (int i=0;i<8;i++){
    int n=n0+i;
    float ig=sigm(a0[i]), fg=sigm(a1[i]), gg=tanhf(a2[i]), og=sigm(a3[i]);
    float cv = c[n*96+j];
    float nc = fg*cv + ig*gg;
    float nv = og*tanhf(nc);
    ncv[i]=nc; nh[i]=nv;
    lh[(g*8+i)*97 + j] = nv;
  }
  __syncthreads();   // all reads of old h done before rewrite
  #pragma unroll
  for (int i=0;i<8;i++){ int n=n0+i; c[n*96+j]=ncv[i]; h[n*96+j]=nh[i]; }

  // next-step A/B from fresh h (in LDS)
  const float* WA = ws + O_W0AT; const float* WB = ws + O_W0BT;
  float aa[8],ab[8];
  #pragma unroll
  for (int i=0;i<8;i++){ aa[i]=0.f; ab[i]=0.f; }
  #pragma unroll 2
  for (int k=0;k<96;k++){
    float wa=WA[k*96+j], wb=WB[k*96+j];
    #pragma unroll
    for (int i=0;i<8;i++){
      float hv = lh[(g*8+i)*97 + k];
      aa[i]=fmaf(wa,hv,aa[i]); ab[i]=fmaf(wb,hv,ab[i]);
    }
  }
  float* Aa=ws+O_A; float* Bb=ws+O_BV;
  float b0v = msgb[j];
  #pragma unroll
  for (int i=0;i<8;i++){ int n=n0+i; Aa[n*96+j]=aa[i]; Bb[n*96+j]=ab[i]+b0v; }

  // logits for this step
  if (j < 80){
    int ln = j/10, cls = j%10;
    int n = n0 + ln;
    float q0=outb[cls], q1=0.f, q2=0.f, q3=0.f;
    const float* hr = &lh[(g*8+ln)*97];
    #pragma unroll
    for (int k=0;k<96;k+=4){
      q0=fmaf(outW[cls*96+k  ],hr[k  ],q0); q1=fmaf(outW[cls*96+k+1],hr[k+1],q1);
      q2=fmaf(outW[cls*96+k+2],hr[k+2],q2); q3=fmaf(outW[cls*96+k+3],hr[k+3],q3);
    }
    float lg = (q0+q1)+(q2+q3);
    lgt[(g*8+ln)*10 + cls] = lg;
    out[165889 + (t*NN + n)*10 + cls] = lg;
  }
  __syncthreads();
  if (j < 8){
    int n = n0 + j;
    const float* L = &lgt[(g*8+j)*10];
    float m = L[0]; int bi = 0;
    #pragma unroll
    for (int cc=1;cc<10;cc++){ if (L[cc] > m){ m=L[cc]; bi=cc; } }
    float se = 0.f;
    #pragma unroll
    for (int cc=0;cc<10;cc++) se += expf(L[cc]-m);
    int lab = labels[n];
    float lp = L[lab] - m - logf(se);
    atomicAdd(ws + O_LOSS, -lp);
    out[t*NN + n] = (float)bi;
  }
}

__global__ void k_final(float* ws, float* out){
  if (threadIdx.x == 0 && blockIdx.x == 0)
    out[165888] = ws[O_LOSS] / (float)(TT*NN);
}

extern "C" void kernel_launch(void* const* d_in, const int* in_sizes, int n_in,
                              void* d_out, int out_size, void* d_ws, size_t ws_size,
                              hipStream_t stream)
{
  (void)in_sizes; (void)n_in; (void)out_size; (void)ws_size;
  const int* q      = (const int*)d_in[0];
  const int* row    = (const int*)d_in[1];
  const int* col    = (const int*)d_in[2];
  const int* labels = (const int*)d_in[3];
  // d_in[4] = src (implied by edge grouping: e in [20n,20n+20) has src==n)
  const int* dst    = (const int*)d_in[5];
  const float* demb  = (const float*)d_in[6];
  const float* remb  = (const float*)d_in[7];
  const float* cemb  = (const float*)d_in[8];
  const float* inW0  = (const float*)d_in[9];
  const float* inW   = (const float*)d_in[10];
  const float* inb   = (const float*)d_in[11];
  const float* msgW0 = (const float*)d_in[12];
  const float* msgW  = (const float*)d_in[13];
  const float* msgb  = (const float*)d_in[14];
  const float* Wih   = (const float*)d_in[15];
  const float* Whh   = (const float*)d_in[16];
  const float* outW  = (const float*)d_in[17];
  const float* outb  = (const float*)d_in[18];

  float* ws  = (float*)d_ws;
  float* out = (float*)d_out;

  hipLaunchKernelGGL(k_convert, dim3(361), dim3(256), 0, stream, ws, msgW0, Whh, Wih);
  hipLaunchKernelGGL(k_wcomb, dim3(144), dim3(256), 0, stream, ws, Wih, msgW, msgb);
  hipLaunchKernelGGL(k_input, dim3(162), dim3(64), 0, stream,
                     ws, q, row, col, demb, remb, cemb, inW0, inW, inb);
  hipLaunchKernelGGL(k_ab0, dim3(648), dim3(192), 0, stream, ws, msgb);
  for (int t=0; t<TT; ++t){
    hipLaunchKernelGGL(k_edge, dim3(1728), dim3(128), 0, stream, ws, dst, msgW, msgb);
    hipLaunchKernelGGL(k_lstm, dim3(648), dim3(192), 0, stream,
                       ws, labels, msgb, outW, outb, out, t);
  }
  hipLaunchKernelGGL(k_final, dim3(1), dim3(64), 0, stream, ws, out);
}